// Round 1
// baseline (527.889 us; speedup 1.0000x reference)
//
#include <hip/hip_runtime.h>
#include <hip/hip_bf16.h>

#define NN 50000
#define EE 600000
#define HH 128
#define OUTD 32
#define RR 64
#define BB 16
#define KK 2048  // BB*HH

typedef short s16x8 __attribute__((ext_vector_type(8)));
typedef float f32x4 __attribute__((ext_vector_type(4)));
typedef unsigned short ushort_t;
typedef unsigned int uint_t;

__device__ inline ushort_t f_to_bf16(float f){
    __hip_bfloat16 h = __float2bfloat16(f);
    return *reinterpret_cast<ushort_t*>(&h);
}

__global__ void zero_i32(int* p, int n){
    int i = blockIdx.x*256 + threadIdx.x;
    if (i < n) p[i] = 0;
}

__global__ void hist_kernel(const int* __restrict__ dst, int* counts){
    int e = blockIdx.x*256 + threadIdx.x;
    if (e < EE) atomicAdd(&counts[dst[e]], 1);
}

// single-block inclusive scan over counts -> offsets[1..N], offsets[0]=0
__global__ void scan_kernel(const int* __restrict__ counts, int* __restrict__ offsets){
    __shared__ int wsum[16];
    __shared__ int carryS;
    int t = threadIdx.x;
    int lane = t & 63, wv = t >> 6;
    if (t == 0){ carryS = 0; offsets[0] = 0; }
    __syncthreads();
    for (int base = 0; base < NN; base += 1024){
        int v = (base + t < NN) ? counts[base + t] : 0;
        int x = v;
        #pragma unroll
        for (int off = 1; off < 64; off <<= 1){
            int y = __shfl_up(x, off, 64);
            if (lane >= off) x += y;
        }
        if (lane == 63) wsum[wv] = x;
        __syncthreads();
        int wpre = 0;
        for (int i = 0; i < wv; i++) wpre += wsum[i];
        int incl = carryS + wpre + x;
        if (base + t < NN) offsets[base + t + 1] = incl;
        __syncthreads();
        if (t == 1023) carryS = incl;
        __syncthreads();
    }
}

__global__ void scatter_kernel(const int* __restrict__ dst, const int* __restrict__ offsets,
                               int* cursor, int* eperm){
    int e = blockIdx.x*256 + threadIdx.x;
    if (e >= EE) return;
    int d = dst[e];
    int r = atomicAdd(&cursor[d], 1);
    eperm[offsets[d] + r] = e;
}

// build transposed bf16 weights: Wt1[o][k] = V1[k][o] (k = b*H+i), Wt2[o][k] = V2[k][o]
__global__ void convw_kernel(const float* __restrict__ V1, const float* __restrict__ V2,
                             ushort_t* __restrict__ Wt1, ushort_t* __restrict__ Wt2){
    int i = blockIdx.x*256 + threadIdx.x;
    if (i < HH*KK){
        int o = i / KK, k = i % KK;
        Wt1[i] = f_to_bf16(V1[(size_t)k*HH + o]);
    } else {
        int j = i - HH*KK;
        if (j < OUTD*KK){
            int o = j / KK, k = j % KK;
            Wt2[j] = f_to_bf16(V2[(size_t)k*OUTD + o]);
        }
    }
}

// one wave per node: agg[v, b, h] = sum_{e: dst=v} comp[etype_e, b] * norm_e * x[src_e, h]
template<bool IN_BF16>
__global__ void aggregate_kernel(const void* __restrict__ xin, const int* __restrict__ src,
                                 const int* __restrict__ etype, const float* __restrict__ norm,
                                 const float* __restrict__ comp, const int* __restrict__ eperm,
                                 const int* __restrict__ offsets,
                                 ushort_t* __restrict__ agg, int v0, int vcount){
    int wave = threadIdx.x >> 6, lane = threadIdx.x & 63;
    int v = v0 + blockIdx.x*4 + wave;
    if (v >= v0 + vcount) return;
    float acc0[BB], acc1[BB];
    #pragma unroll
    for (int b = 0; b < BB; b++){ acc0[b] = 0.f; acc1[b] = 0.f; }
    int beg = offsets[v], end = offsets[v+1];
    for (int p = beg; p < end; ++p){
        int e = eperm[p];
        int s = src[e];
        int et = etype[e];
        float nr = norm[e];
        float xa, xb;
        if (IN_BF16){
            uint_t u = *reinterpret_cast<const uint_t*>(
                reinterpret_cast<const ushort_t*>(xin) + (size_t)s*HH + 2*lane);
            xa = __uint_as_float((u & 0xffffu) << 16);
            xb = __uint_as_float(u & 0xffff0000u);
        } else {
            const float* xp = reinterpret_cast<const float*>(xin) + (size_t)s*HH + 2*lane;
            xa = xp[0]; xb = xp[1];
        }
        const float* cr = comp + et*BB;
        #pragma unroll
        for (int b = 0; b < BB; b++){
            float c = cr[b] * nr;
            acc0[b] = fmaf(c, xa, acc0[b]);
            acc1[b] = fmaf(c, xb, acc1[b]);
        }
    }
    size_t base = (size_t)(v - v0)*KK + 2*lane;
    #pragma unroll
    for (int b = 0; b < BB; b++){
        uint_t pk = (uint_t)f_to_bf16(acc0[b]) | ((uint_t)f_to_bf16(acc1[b]) << 16);
        *reinterpret_cast<uint_t*>(agg + base + b*HH) = pk;
    }
}

// C[m, o] = sum_k A[m,k] * Wt[o,k]  (+bias, opt relu). A: [mcount, 2048] bf16 chunk-local.
template<int BN, bool RELU, bool OUT_BF16>
__global__ __launch_bounds__(256) void gemm_kernel(const ushort_t* __restrict__ A,
                                                   const ushort_t* __restrict__ Wt,
                                                   const float* __restrict__ bias,
                                                   void* __restrict__ Cout, int mcount){
    __shared__ ushort_t Alds[64][72];
    __shared__ ushort_t Blds[BN][72];
    int tid = threadIdx.x;
    int m0 = blockIdx.x*64;
    int wave = tid >> 6, lane = tid & 63;
    f32x4 acc[BN/16];
    #pragma unroll
    for (int i = 0; i < BN/16; i++)
        #pragma unroll
        for (int j = 0; j < 4; j++) acc[i][j] = 0.f;

    int arow = wave*16 + (lane & 15);
    int kidx = (lane >> 4) * 8;

    for (int k0 = 0; k0 < KK; k0 += 64){
        // stage A tile 64x64 (8 x 16B chunks per row)
        #pragma unroll
        for (int i = 0; i < 2; i++){
            int c = tid + i*256;
            int row = c >> 3, ko = (c & 7) * 8;
            uint4 val = make_uint4(0u, 0u, 0u, 0u);
            if (m0 + row < mcount)
                val = *reinterpret_cast<const uint4*>(A + (size_t)(m0 + row)*KK + k0 + ko);
            *reinterpret_cast<uint4*>(&Alds[row][ko]) = val;
        }
        // stage Bt tile BN x 64
        #pragma unroll
        for (int i = 0; i < BN/32; i++){
            int c = tid + i*256;
            int row = c >> 3, ko = (c & 7) * 8;
            *reinterpret_cast<uint4*>(&Blds[row][ko]) =
                *reinterpret_cast<const uint4*>(Wt + (size_t)row*KK + k0 + ko);
        }
        __syncthreads();
        #pragma unroll
        for (int ks = 0; ks < 2; ks++){
            int ak = ks*32 + kidx;
            s16x8 a = *reinterpret_cast<const s16x8*>(&Alds[arow][ak]);
            #pragma unroll
            for (int nt = 0; nt < BN/16; nt++){
                s16x8 b = *reinterpret_cast<const s16x8*>(&Blds[nt*16 + (lane & 15)][ak]);
                acc[nt] = __builtin_amdgcn_mfma_f32_16x16x32_bf16(a, b, acc[nt], 0, 0, 0);
            }
        }
        __syncthreads();
    }
    // epilogue: D row = (lane>>4)*4 + r, col = lane&15 (verified gfx950 C/D mapping)
    int rbase = m0 + wave*16 + ((lane >> 4) << 2);
    int cbase = lane & 15;
    #pragma unroll
    for (int nt = 0; nt < BN/16; nt++){
        int col = nt*16 + cbase;
        float bv = bias[col];
        #pragma unroll
        for (int r = 0; r < 4; r++){
            int row = rbase + r;
            if (row < mcount){
                float val = acc[nt][r] + bv;
                if (RELU) val = fmaxf(val, 0.f);
                if (OUT_BF16)
                    reinterpret_cast<ushort_t*>(Cout)[(size_t)row*BN + col] = f_to_bf16(val);
                else
                    reinterpret_cast<float*>(Cout)[(size_t)row*BN + col] = val;
            }
        }
    }
}

extern "C" void kernel_launch(void* const* d_in, const int* in_sizes, int n_in,
                              void* d_out, int out_size, void* d_ws, size_t ws_size,
                              hipStream_t stream){
    const int*   src   = (const int*)d_in[0];
    const int*   dst   = (const int*)d_in[1];
    const int*   etype = (const int*)d_in[2];
    const float* norm  = (const float*)d_in[3];
    const float* emb   = (const float*)d_in[4];
    const float* V1    = (const float*)d_in[5];
    const float* comp1 = (const float*)d_in[6];
    const float* bias1 = (const float*)d_in[7];
    const float* V2    = (const float*)d_in[8];
    const float* comp2 = (const float*)d_in[9];
    const float* bias2 = (const float*)d_in[10];
    float* out = (float*)d_out;

    char* w = (char*)d_ws;
    auto alloc = [&](size_t bytes) -> char* {
        char* p = w; w += (bytes + 255) & ~(size_t)255; return p;
    };
    int*      offsets = (int*)alloc((NN + 1) * 4);
    int*      counts  = (int*)alloc(NN * 4);
    int*      cursor  = (int*)alloc(NN * 4);
    int*      eperm   = (int*)alloc(EE * 4);
    ushort_t* Wt1     = (ushort_t*)alloc((size_t)HH * KK * 2);
    ushort_t* Wt2     = (ushort_t*)alloc((size_t)OUTD * KK * 2);
    ushort_t* h       = (ushort_t*)alloc((size_t)NN * HH * 2);
    size_t used  = (size_t)(w - (char*)d_ws);
    size_t avail = ws_size > used ? ws_size - used : 0;
    int chunkN = (int)(avail / ((size_t)KK * 2));
    chunkN &= ~63;
    if (chunkN < 64) chunkN = 64;       // hope ws is big enough; nothing better to do
    if (chunkN > NN) chunkN = NN;
    ushort_t* agg = (ushort_t*)w;

    // CSR build
    zero_i32<<<(NN + 255)/256, 256, 0, stream>>>(counts, NN);
    zero_i32<<<(NN + 255)/256, 256, 0, stream>>>(cursor, NN);
    hist_kernel<<<(EE + 255)/256, 256, 0, stream>>>(dst, counts);
    scan_kernel<<<1, 1024, 0, stream>>>(counts, offsets);
    scatter_kernel<<<(EE + 255)/256, 256, 0, stream>>>(dst, offsets, cursor, eperm);
    convw_kernel<<<((HH + OUTD)*KK + 255)/256, 256, 0, stream>>>(V1, V2, Wt1, Wt2);

    // layer 1: emb (f32) -> h (bf16, relu)
    for (int v0 = 0; v0 < NN; v0 += chunkN){
        int vc = (NN - v0 < chunkN) ? (NN - v0) : chunkN;
        aggregate_kernel<false><<<(vc + 3)/4, 256, 0, stream>>>(
            emb, src, etype, norm, comp1, eperm, offsets, agg, v0, vc);
        gemm_kernel<128, true, true><<<(vc + 63)/64, 256, 0, stream>>>(
            agg, Wt1, bias1, h + (size_t)v0 * HH, vc);
    }
    // layer 2: h (bf16) -> out (f32)
    for (int v0 = 0; v0 < NN; v0 += chunkN){
        int vc = (NN - v0 < chunkN) ? (NN - v0) : chunkN;
        aggregate_kernel<true><<<(vc + 3)/4, 256, 0, stream>>>(
            h, src, etype, norm, comp2, eperm, offsets, agg, v0, vc);
        gemm_kernel<32, false, false><<<(vc + 63)/64, 256, 0, stream>>>(
            agg, Wt2, bias2, out + (size_t)v0 * OUTD, vc);
    }
}